// Round 7
// baseline (845.430 us; speedup 1.0000x reference)
//
#include <hip/hip_runtime.h>

// B=512, V=256, W=64, H=64. Outputs: x_tilde_seq (64,512,256) fp32, h_seq (64,512,64) fp32.
// One block = ONE batch; 512 blocks, 512 threads, 2 blocks/CU (launch_bounds(512,4)).
// Cross-block overlap fills barrier stalls (R6 was 1 block/CU, VALUBusy 40%).
// 4 barriers/step: P1 wout | P2 score+e+wave-sums | P4 gates(linear in e*x, scaled by r) | P5 cell.
// Persistent regs ~96: w_ih fp16 (64), w_hh fp16 (16), w_w fp32 slice (16).

#define KLOG2E  1.4426950408889634f   // log2(e)
#define K2LOG2E 2.8853900817779268f   // 2*log2(e)

typedef _Float16 h2 __attribute__((ext_vector_type(2)));
union H2U { h2 h; unsigned u; };

__device__ __forceinline__ float frcp(float x)  { return __builtin_amdgcn_rcpf(x); }
__device__ __forceinline__ float fexp2(float x) { return __builtin_amdgcn_exp2f(x); }
__device__ __forceinline__ float fsigmoid(float x) { return frcp(1.f + fexp2(-KLOG2E * x)); }
__device__ __forceinline__ float ftanh(float x) { return 1.f - 2.f * frcp(fexp2(K2LOG2E * x) + 1.f); }

#if __has_builtin(__builtin_amdgcn_fdot2)
__device__ __forceinline__ float fdot2(h2 a, h2 b, float c) { return __builtin_amdgcn_fdot2(a, b, c, false); }
#else
__device__ __forceinline__ float fdot2(h2 a, h2 b, float c) { return c + (float)a.x*(float)b.x + (float)a.y*(float)b.y; }
#endif

__device__ __forceinline__ unsigned pkrtz_u(float a, float b) {
#if __has_builtin(__builtin_amdgcn_cvt_pkrtz)
    H2U r; r.h = __builtin_bit_cast(h2, __builtin_amdgcn_cvt_pkrtz(a, b)); return r.u;
#else
    H2U r; r.h.x = (_Float16)a; r.h.y = (_Float16)b; return r.u;
#endif
}
__device__ __forceinline__ h2 pk_rtn(float a, float b) {   // round-to-nearest (weights)
    h2 r; r.x = (_Float16)a; r.y = (_Float16)b; return r;
}

// LDS layout (float slots)
#define L_E    0                    // E [256][68] fp32 = exp(2*(u_out+b_u))
#define L_PS   17408                // gate partials [512] (2 sg-slices x 256)
#define L_EXF  17920                // e*x fp32 [256]
#define L_XH   18176                // e*x packed h2 [128 uints]
#define L_EW   18304                // e_w [64]
#define L_HC   18368                // h||c fp32 [128]
#define L_HCH  18496                // h packed h2 [32 uints]
#define L_BI   18528                // bias b_ih+b_hh [256]
#define L_WV   18784                // -2*w_v [64]
#define L_WS   18848                // wave e-sums [8]
#define L_TOT  18856                // 75424 bytes; x2 blocks = 150848 <= 160K/CU

__global__ __launch_bounds__(512, 4) void enc_kernel(
    const float* __restrict__ x,     // (512,256,64)
    const float* __restrict__ w_ih,  // (256,256)
    const float* __restrict__ w_hh,  // (256,64)
    const float* __restrict__ b_ih,  // (256)
    const float* __restrict__ b_hh,  // (256)
    const float* __restrict__ w_v,   // (64)
    const float* __restrict__ w_w,   // (64,128)
    const float* __restrict__ b_w,   // (64)
    const float* __restrict__ w_u,   // (64,64)
    const float* __restrict__ b_u,   // (64)
    float* __restrict__ out_xt,      // (64,512,256)
    float* __restrict__ out_h)       // (64,512,64)
{
    extern __shared__ float lds[];
    float*    E     = lds + L_E;
    float*    ps    = lds + L_PS;
    float*    exf   = lds + L_EXF;
    unsigned* xh    = (unsigned*)(lds + L_XH);
    float*    ew    = lds + L_EW;
    float*    hc    = lds + L_HC;
    unsigned* hch   = (unsigned*)(lds + L_HCH);
    float*    biasL = lds + L_BI;
    float*    wv2L  = lds + L_WV;
    float*    wsum  = lds + L_WS;

    const int tid  = threadIdx.x;
    const int lane = tid & 63;
    const int wvi  = tid >> 6;          // wave 0..7
    const int b    = blockIdx.x;        // one batch per block
    const int j    = tid & 255;         // gate-output row / v index
    const int sg   = tid >> 8;          // 0/1: v-slice [sg*128,+128), k-slice [sg*32,+32)

    // ---- one-time LDS fills ----
    if (tid < 256) biasL[tid] = b_ih[tid] + b_hh[tid];
    if (tid < 64)  wv2L[tid] = -2.f * w_v[tid];
    if (tid < 128) hc[tid] = 0.f;
    if (tid < 32)  hch[tid] = 0u;

    float Sv = 0.f;
#pragma unroll
    for (int wi = 0; wi < 64; ++wi) Sv += w_v[wi];   // uniform scalar loads
    const float bu_lane = b_u[lane];

    // ---- E init (before weight loads: keeps init register peak low) ----
    // E[v][w] = exp(2*(x[b,v,:]@w_u[w,:] + b_u[w])); wave wvi covers rows [wvi*32,+32)
#pragma unroll 1
    for (int half = 0; half < 2; ++half) {
        float4 wu_r[8];
#pragma unroll
        for (int i = 0; i < 8; ++i)
            wu_r[i] = *(const float4*)&w_u[lane*64 + half*32 + 4*i];
        const float* xb = x + b*16384 + half*32;
#pragma unroll 2
        for (int vi = 0; vi < 32; ++vi) {
            int v = __builtin_amdgcn_readfirstlane(wvi*32 + vi);
            const float4* xr = (const float4*)(xb + v*64);
            float acc = 0.f;
#pragma unroll
            for (int i = 0; i < 8; ++i) {
                float4 xx = xr[i]; float4 wu = wu_r[i];
                acc += xx.x*wu.x + xx.y*wu.y + xx.z*wu.z + xx.w*wu.w;
            }
            if (half == 0) E[v*68 + lane] = acc + bu_lane;
            else           E[v*68 + lane] = fexp2(K2LOG2E * (E[v*68 + lane] + acc));
        }
    }
    __syncthreads();

    // ---- persistent per-thread weights (after init) ----
    // gates: thread (j, sg): output row j over v-slice [sg*128,+128) fp16
    h2 wihr2[64];
    {
        const float4* g4 = (const float4*)(w_ih + j*256 + sg*128);
#pragma unroll
        for (int i = 0; i < 32; ++i) {
            float4 v4 = g4[i];
            wihr2[2*i]     = pk_rtn(v4.x, v4.y);
            wihr2[2*i + 1] = pk_rtn(v4.z, v4.w);
        }
    }
    h2 whh2[16];   // w_hh row j, k-slice [sg*32,+32) fp16
    {
        const float4* h4 = (const float4*)(w_hh + j*64 + sg*32);
#pragma unroll
        for (int i = 0; i < 8; ++i) {
            float4 v4 = h4[i];
            whh2[2*i]     = pk_rtn(v4.x, v4.y);
            whh2[2*i + 1] = pk_rtn(v4.z, v4.w);
        }
    }
    // wout: thread (w8 = wvi*8+(lane&7), kg = lane>>3), k = kg*4 + 32m
    const int w8 = wvi*8 + (lane & 7);
    const int kg = lane >> 3;
    float4 www4[4];
#pragma unroll
    for (int m = 0; m < 4; ++m)
        www4[m] = *(const float4*)&w_w[w8*128 + kg*4 + 32*m];
    const float bwr = b_w[w8];

    const float* xrow = x + b*16384 + j*64;
    float xcur = xrow[0];

    for (int t = 0; t < 64; ++t) {
        // ---- P1: wout -> ew (all threads; conflict-free interleaved hc reads) ----
        {
            float acc = 0.f;
#pragma unroll
            for (int m = 0; m < 4; ++m) {
                float4 w4 = www4[m];
                float4 hv = *(const float4*)&hc[kg*4 + 32*m];
                acc += hv.x*w4.x + hv.y*w4.y + hv.z*w4.z + hv.w*w4.w;
            }
#pragma unroll
            for (int off = 8; off <= 32; off <<= 1)
                acc += __shfl_xor(acc, off, 64);
            if (kg == 0) ew[w8] = fexp2(K2LOG2E * (acc + bwr));
        }
        float xnxt = (t < 63) ? xrow[t + 1] : 0.f;   // prefetch across B1
        __syncthreads();   // B1

        // ---- P2: score -> e, e*x; wave sums (threads 0-255; waves 4-7 idle,
        //      covered by the co-resident block) ----
        if (tid < 256) {
            float acc = Sv;
            const float* Erow = E + j*68;
#pragma unroll
            for (int q = 0; q < 16; ++q) {
                float4 e4 = *(const float4*)&Erow[4*q];
                float4 c4 = *(const float4*)&ew[4*q];     // broadcast
                float4 v4 = *(const float4*)&wv2L[4*q];   // broadcast
                acc += v4.x * frcp(e4.x*c4.x + 1.f);
                acc += v4.y * frcp(e4.y*c4.y + 1.f);
                acc += v4.z * frcp(e4.z*c4.z + 1.f);
                acc += v4.w * frcp(e4.w*c4.w + 1.f);
            }
            float e  = fexp2(KLOG2E * acc);   // |score| <= sum|w_v| ~2.6: no max-subtract
            float ex = e * xcur;
            float s = e;
#pragma unroll
            for (int off = 1; off <= 32; off <<= 1) s += __shfl_xor(s, off, 64);
            if (lane == 0) wsum[wvi] = s;
            exf[j] = ex;
            float exp2v = __shfl_xor(ex, 1, 64);
            if (!(lane & 1)) xh[j >> 1] = pkrtz_u(ex, exp2v);
        }
        xcur = xnxt;
        __syncthreads();   // B2

        // ---- P4: gates partials on e*x (scale by r at end) + out_xt store ----
        {
            float r = frcp(wsum[0] + wsum[1] + wsum[2] + wsum[3]);
            if (sg == 0) out_xt[t*131072 + b*256 + j] = r * exf[j];

            float a = 0.f;
            const uint4* xx = (const uint4*)xh + sg*16;   // wave-uniform broadcast
#pragma unroll
            for (int i = 0; i < 16; ++i) {
                uint4 u = xx[i];
                H2U p0, p1, p2, p3;
                p0.u = u.x; p1.u = u.y; p2.u = u.z; p3.u = u.w;
                a = fdot2(p0.h, wihr2[4*i + 0], a);
                a = fdot2(p1.h, wihr2[4*i + 1], a);
                a = fdot2(p2.h, wihr2[4*i + 2], a);
                a = fdot2(p3.h, wihr2[4*i + 3], a);
            }
            float ah = 0.f;
            const uint4* hh = (const uint4*)hch + sg*4;   // h fp16, broadcast
#pragma unroll
            for (int i = 0; i < 4; ++i) {
                uint4 u = hh[i];
                H2U p0, p1, p2, p3;
                p0.u = u.x; p1.u = u.y; p2.u = u.z; p3.u = u.w;
                ah = fdot2(p0.h, whh2[4*i + 0], ah);
                ah = fdot2(p1.h, whh2[4*i + 1], ah);
                ah = fdot2(p2.h, whh2[4*i + 2], ah);
                ah = fdot2(p3.h, whh2[4*i + 3], ah);
            }
            ps[sg*256 + j] = r*a + ah;
        }
        __syncthreads();   // B4

        // ---- P5: LSTM cell (wave 0 only; other block's waves fill the gap) ----
        if (wvi == 0) {
            const int k = lane;
            float gi = biasL[k      ] + ps[k      ] + ps[256 + k      ];
            float gf = biasL[64  + k] + ps[64  + k] + ps[256 + 64  + k];
            float gg = biasL[128 + k] + ps[128 + k] + ps[256 + 128 + k];
            float go = biasL[192 + k] + ps[192 + k] + ps[256 + 192 + k];
            gi = fsigmoid(gi); gf = fsigmoid(gf);
            gg = ftanh(gg);    go = fsigmoid(go);
            float cn = gf * hc[64 + k] + gi * gg;
            float hn = go * ftanh(cn);
            hc[k] = hn; hc[64 + k] = cn;
            float hp = __shfl_xor(hn, 1, 64);
            if (!(lane & 1)) hch[k >> 1] = pkrtz_u(hn, hp);
            out_h[t*32768 + b*64 + k] = hn;
        }
        __syncthreads();   // B5
    }
}

extern "C" void kernel_launch(void* const* d_in, const int* in_sizes, int n_in,
                              void* d_out, int out_size, void* d_ws, size_t ws_size,
                              hipStream_t stream) {
    const float* x    = (const float*)d_in[0];
    const float* w_ih = (const float*)d_in[1];
    const float* w_hh = (const float*)d_in[2];
    const float* b_ih = (const float*)d_in[3];
    const float* b_hh = (const float*)d_in[4];
    const float* w_v  = (const float*)d_in[5];
    const float* w_w  = (const float*)d_in[6];
    const float* b_w  = (const float*)d_in[7];
    const float* w_u  = (const float*)d_in[8];
    const float* b_u  = (const float*)d_in[9];

    float* out_xt = (float*)d_out;
    float* out_h  = out_xt + 64*512*256;

    const size_t shbytes = (size_t)L_TOT * sizeof(float);  // 75424 B
    (void)hipFuncSetAttribute((const void*)enc_kernel,
                        hipFuncAttributeMaxDynamicSharedMemorySize, (int)shbytes);
    enc_kernel<<<dim3(512), dim3(512), shbytes, stream>>>(
        x, w_ih, w_hh, b_ih, b_hh, w_v, w_w, b_w, w_u, b_u, out_xt, out_h);
}

// Round 8
// 337.299 us; speedup vs baseline: 2.5065x; 2.5065x over previous
//
#include <hip/hip_runtime.h>

// B=512, V=256, W=64, H=64. Outputs: x_tilde_seq (64,512,256) fp32, h_seq (64,512,64) fp32.
// One block = TWO batches (bA, bA+256) interleaved per step; 256 blocks x 512 thr, 1 block/CU.
// R6 phase plan (4 barriers/step, softmax scale deferred into gates) + dual-batch ILP:
// every phase carries two independent dependency chains, halving barrier cost per batch-step.
// Persistent regs ~96 (batch-independent): w_ih fp16 (64), w_hh fp16 (16), w_w fp32 (16).

#define KLOG2E  1.4426950408889634f   // log2(e)
#define K2LOG2E 2.8853900817779268f   // 2*log2(e)

typedef _Float16 h2 __attribute__((ext_vector_type(2)));
union H2U { h2 h; unsigned u; };

__device__ __forceinline__ float frcp(float x)  { return __builtin_amdgcn_rcpf(x); }
__device__ __forceinline__ float fexp2(float x) { return __builtin_amdgcn_exp2f(x); }
__device__ __forceinline__ float fsigmoid(float x) { return frcp(1.f + fexp2(-KLOG2E * x)); }
__device__ __forceinline__ float ftanh(float x) { return 1.f - 2.f * frcp(fexp2(K2LOG2E * x) + 1.f); }

#if __has_builtin(__builtin_amdgcn_fdot2)
__device__ __forceinline__ float fdot2(h2 a, h2 b, float c) { return __builtin_amdgcn_fdot2(a, b, c, false); }
#else
__device__ __forceinline__ float fdot2(h2 a, h2 b, float c) { return c + (float)a.x*(float)b.x + (float)a.y*(float)b.y; }
#endif

__device__ __forceinline__ unsigned pkrtz_u(float a, float b) {
#if __has_builtin(__builtin_amdgcn_cvt_pkrtz)
    H2U r; r.h = __builtin_bit_cast(h2, __builtin_amdgcn_cvt_pkrtz(a, b)); return r.u;
#else
    H2U r; r.h.x = (_Float16)a; r.h.y = (_Float16)b; return r.u;
#endif
}
__device__ __forceinline__ h2 pk_rtn(float a, float b) {   // round-to-nearest (weights)
    h2 r; r.x = (_Float16)a; r.y = (_Float16)b; return r;
}

// LDS layout (float slots)
#define L_EA   0                    // E_A [256][68] fp32
#define L_EB   17408                // E_B [256][68]
#define L_PSA  34816                // gate partials A [512]
#define L_PSB  35328
#define L_EXFA 35840                // e*x fp32 A [256]
#define L_EXFB 36096
#define L_XHA  36352                // e*x packed h2 A [128 u32]
#define L_XHB  36480
#define L_EWA  36608                // e_w A [64]
#define L_EWB  36672
#define L_HCA  36736                // h||c fp32 A [128]
#define L_HCB  36864
#define L_HHA  36992                // h packed h2 A [32 u32]
#define L_HHB  37024
#define L_BI   37056                // bias b_ih+b_hh [256]
#define L_WV   37312                // -2*w_v [64]
#define L_WS   37376                // wave e-sums [8]: 0-3 = A, 4-7 = B
#define L_TOT  37392                // 149568 bytes <= 160K (1 block/CU)

__global__ __launch_bounds__(512, 2) void enc_kernel(
    const float* __restrict__ x,     // (512,256,64)
    const float* __restrict__ w_ih,  // (256,256)
    const float* __restrict__ w_hh,  // (256,64)
    const float* __restrict__ b_ih,  // (256)
    const float* __restrict__ b_hh,  // (256)
    const float* __restrict__ w_v,   // (64)
    const float* __restrict__ w_w,   // (64,128)
    const float* __restrict__ b_w,   // (64)
    const float* __restrict__ w_u,   // (64,64)
    const float* __restrict__ b_u,   // (64)
    float* __restrict__ out_xt,      // (64,512,256)
    float* __restrict__ out_h)       // (64,512,64)
{
    extern __shared__ float lds[];
    float*    EA   = lds + L_EA;    float*    EB   = lds + L_EB;
    float*    psA  = lds + L_PSA;   float*    psB  = lds + L_PSB;
    float*    exfA = lds + L_EXFA;  float*    exfB = lds + L_EXFB;
    unsigned* xhA  = (unsigned*)(lds + L_XHA);
    unsigned* xhB  = (unsigned*)(lds + L_XHB);
    float*    ewA  = lds + L_EWA;   float*    ewB  = lds + L_EWB;
    float*    hcA  = lds + L_HCA;   float*    hcB  = lds + L_HCB;
    unsigned* hhA  = (unsigned*)(lds + L_HHA);
    unsigned* hhB  = (unsigned*)(lds + L_HHB);
    float*    biasL= lds + L_BI;
    float*    wv2L = lds + L_WV;
    float*    wsum = lds + L_WS;

    const int tid  = threadIdx.x;
    const int lane = tid & 63;
    const int wvi  = tid >> 6;          // wave 0..7
    const int bA   = blockIdx.x;
    const int bB   = blockIdx.x + 256;
    const int j    = tid & 255;         // gate row / v index
    const int sg   = tid >> 8;          // 0/1: v-slice [sg*128,+128), k-slice [sg*32,+32)

    // ---- one-time LDS fills ----
    if (tid < 256) biasL[tid] = b_ih[tid] + b_hh[tid];
    if (tid < 64)  wv2L[tid] = -2.f * w_v[tid];
    if (tid < 128) { hcA[tid] = 0.f; hcB[tid] = 0.f; }
    if (tid < 32)  { hhA[tid] = 0u; hhB[tid] = 0u; }

    float Sv = 0.f;
#pragma unroll
    for (int wi = 0; wi < 64; ++wi) Sv += w_v[wi];   // uniform scalar loads
    const float bu_lane = b_u[lane];

    // ---- E init (both batches, before weight loads to keep init reg-peak low) ----
#pragma unroll 1
    for (int bb = 0; bb < 2; ++bb) {
        float* E = bb ? EB : EA;
        const int b = bb ? bB : bA;
#pragma unroll 1
        for (int half = 0; half < 2; ++half) {
            float4 wu_r[8];
#pragma unroll
            for (int i = 0; i < 8; ++i)
                wu_r[i] = *(const float4*)&w_u[lane*64 + half*32 + 4*i];
            const float* xb = x + b*16384 + half*32;
#pragma unroll 2
            for (int vi = 0; vi < 32; ++vi) {
                int v = __builtin_amdgcn_readfirstlane(wvi*32 + vi);
                const float4* xr = (const float4*)(xb + v*64);
                float acc = 0.f;
#pragma unroll
                for (int i = 0; i < 8; ++i) {
                    float4 xx = xr[i]; float4 wu = wu_r[i];
                    acc += xx.x*wu.x + xx.y*wu.y + xx.z*wu.z + xx.w*wu.w;
                }
                if (half == 0) E[v*68 + lane] = acc + bu_lane;
                else           E[v*68 + lane] = fexp2(K2LOG2E * (E[v*68 + lane] + acc));
            }
        }
    }
    __syncthreads();

    // ---- persistent per-thread weights (after init) ----
    h2 wihr2[64];   // w_ih row j, v-slice [sg*128,+128) fp16
    {
        const float4* g4 = (const float4*)(w_ih + j*256 + sg*128);
#pragma unroll
        for (int i = 0; i < 32; ++i) {
            float4 v4 = g4[i];
            wihr2[2*i]     = pk_rtn(v4.x, v4.y);
            wihr2[2*i + 1] = pk_rtn(v4.z, v4.w);
        }
    }
    h2 whh2[16];    // w_hh row j, k-slice [sg*32,+32) fp16
    {
        const float4* h4 = (const float4*)(w_hh + j*64 + sg*32);
#pragma unroll
        for (int i = 0; i < 8; ++i) {
            float4 v4 = h4[i];
            whh2[2*i]     = pk_rtn(v4.x, v4.y);
            whh2[2*i + 1] = pk_rtn(v4.z, v4.w);
        }
    }
    // wout: thread (w8 = wvi*8+(lane&7), kg = lane>>3) covers k = kg*4 + 32m
    const int w8 = wvi*8 + (lane & 7);
    const int kg = lane >> 3;
    float4 www4[4];
#pragma unroll
    for (int m = 0; m < 4; ++m)
        www4[m] = *(const float4*)&w_w[w8*128 + kg*4 + 32*m];
    const float bwr = b_w[w8];

    // P2 identity: (xj = j, batch = sg)
    const float* xrow = x + (sg ? bB : bA)*16384 + j*64;
    const float* Erow = (sg ? EB : EA) + j*68;
    const float* ewX  = sg ? ewB : ewA;
    float*       exfX = sg ? exfB : exfA;
    unsigned*    xhX  = sg ? xhB : xhA;
    float xcur = xrow[0];

    for (int t = 0; t < 64; ++t) {
        // ---- P1: wout for BOTH batches (dual ILP chains) ----
        {
            float accA = 0.f, accB = 0.f;
#pragma unroll
            for (int m = 0; m < 4; ++m) {
                float4 w4 = www4[m];
                float4 hA = *(const float4*)&hcA[kg*4 + 32*m];
                float4 hB = *(const float4*)&hcB[kg*4 + 32*m];
                accA += hA.x*w4.x + hA.y*w4.y + hA.z*w4.z + hA.w*w4.w;
                accB += hB.x*w4.x + hB.y*w4.y + hB.z*w4.z + hB.w*w4.w;
            }
#pragma unroll
            for (int off = 8; off <= 32; off <<= 1) {
                accA += __shfl_xor(accA, off, 64);
                accB += __shfl_xor(accB, off, 64);
            }
            if (kg == 0)      ewA[w8] = fexp2(K2LOG2E * (accA + bwr));
            else if (kg == 1) ewB[w8] = fexp2(K2LOG2E * (accB + bwr));
        }
        float xnxt = (t < 63) ? xrow[t + 1] : 0.f;   // prefetch across B1
        __syncthreads();   // B1

        // ---- P2: score -> e, e*x (all 8 waves; waves 0-3 = A, 4-7 = B) ----
        {
            float acc = Sv;
#pragma unroll
            for (int q = 0; q < 16; ++q) {
                float4 e4 = *(const float4*)&Erow[4*q];
                float4 c4 = *(const float4*)&ewX[4*q];    // broadcast
                float4 v4 = *(const float4*)&wv2L[4*q];   // broadcast
                acc += v4.x * frcp(e4.x*c4.x + 1.f);
                acc += v4.y * frcp(e4.y*c4.y + 1.f);
                acc += v4.z * frcp(e4.z*c4.z + 1.f);
                acc += v4.w * frcp(e4.w*c4.w + 1.f);
            }
            float e  = fexp2(KLOG2E * acc);  // |score| <= sum|w_v| ~2.6: no max-subtract
            float ex = e * xcur;
            float s = e;
#pragma unroll
            for (int off = 1; off <= 32; off <<= 1) s += __shfl_xor(s, off, 64);
            if (lane == 0) wsum[wvi] = s;
            exfX[j] = ex;
            float exp2v = __shfl_xor(ex, 1, 64);
            if (!(lane & 1)) xhX[j >> 1] = pkrtz_u(ex, exp2v);
        }
        xcur = xnxt;
        __syncthreads();   // B2

        // ---- P4: gates partials for BOTH batches + out_xt stores ----
        {
            float rA = frcp((wsum[0] + wsum[1]) + (wsum[2] + wsum[3]));
            float rB = frcp((wsum[4] + wsum[5]) + (wsum[6] + wsum[7]));
            if (sg == 0) out_xt[t*131072 + bA*256 + j] = rA * exfA[j];
            else         out_xt[t*131072 + bB*256 + j] = rB * exfB[j];

            float aA = 0.f, aB = 0.f;
            const uint4* xxA = (const uint4*)xhA + sg*16;   // wave-uniform broadcast
            const uint4* xxB = (const uint4*)xhB + sg*16;
#pragma unroll
            for (int i = 0; i < 16; ++i) {
                uint4 ua = xxA[i], ub = xxB[i];
                H2U a0, a1, a2, a3, b0, b1, b2, b3;
                a0.u = ua.x; a1.u = ua.y; a2.u = ua.z; a3.u = ua.w;
                b0.u = ub.x; b1.u = ub.y; b2.u = ub.z; b3.u = ub.w;
                aA = fdot2(a0.h, wihr2[4*i + 0], aA);
                aA = fdot2(a1.h, wihr2[4*i + 1], aA);
                aA = fdot2(a2.h, wihr2[4*i + 2], aA);
                aA = fdot2(a3.h, wihr2[4*i + 3], aA);
                aB = fdot2(b0.h, wihr2[4*i + 0], aB);
                aB = fdot2(b1.h, wihr2[4*i + 1], aB);
                aB = fdot2(b2.h, wihr2[4*i + 2], aB);
                aB = fdot2(b3.h, wihr2[4*i + 3], aB);
            }
            float ahA = 0.f, ahB = 0.f;
            const uint4* hha = (const uint4*)hhA + sg*4;    // broadcast
            const uint4* hhb = (const uint4*)hhB + sg*4;
#pragma unroll
            for (int i = 0; i < 4; ++i) {
                uint4 ua = hha[i], ub = hhb[i];
                H2U a0, a1, a2, a3, b0, b1, b2, b3;
                a0.u = ua.x; a1.u = ua.y; a2.u = ua.z; a3.u = ua.w;
                b0.u = ub.x; b1.u = ub.y; b2.u = ub.z; b3.u = ub.w;
                ahA = fdot2(a0.h, whh2[4*i + 0], ahA);
                ahA = fdot2(a1.h, whh2[4*i + 1], ahA);
                ahA = fdot2(a2.h, whh2[4*i + 2], ahA);
                ahA = fdot2(a3.h, whh2[4*i + 3], ahA);
                ahB = fdot2(b0.h, whh2[4*i + 0], ahB);
                ahB = fdot2(b1.h, whh2[4*i + 1], ahB);
                ahB = fdot2(b2.h, whh2[4*i + 2], ahB);
                ahB = fdot2(b3.h, whh2[4*i + 3], ahB);
            }
            psA[sg*256 + j] = rA*aA + ahA;
            psB[sg*256 + j] = rB*aB + ahB;
        }
        __syncthreads();   // B4

        // ---- P5: LSTM cell (wave0 = A, wave1 = B) ----
        if (wvi < 2) {
            float*    ps = wvi ? psB : psA;
            float*    hc = wvi ? hcB : hcA;
            unsigned* hh = wvi ? hhB : hhA;
            float*    oh = out_h + t*32768 + (wvi ? bB : bA)*64;
            const int k = lane;
            float gi = biasL[k      ] + ps[k      ] + ps[256 + k      ];
            float gf = biasL[64  + k] + ps[64  + k] + ps[256 + 64  + k];
            float gg = biasL[128 + k] + ps[128 + k] + ps[256 + 128 + k];
            float go = biasL[192 + k] + ps[192 + k] + ps[256 + 192 + k];
            gi = fsigmoid(gi); gf = fsigmoid(gf);
            gg = ftanh(gg);    go = fsigmoid(go);
            float cn = gf * hc[64 + k] + gi * gg;
            float hn = go * ftanh(cn);
            hc[k] = hn; hc[64 + k] = cn;
            float hp = __shfl_xor(hn, 1, 64);
            if (!(lane & 1)) hh[k >> 1] = pkrtz_u(hn, hp);
            oh[k] = hn;
        }
        __syncthreads();   // B5
    }
}

extern "C" void kernel_launch(void* const* d_in, const int* in_sizes, int n_in,
                              void* d_out, int out_size, void* d_ws, size_t ws_size,
                              hipStream_t stream) {
    const float* x    = (const float*)d_in[0];
    const float* w_ih = (const float*)d_in[1];
    const float* w_hh = (const float*)d_in[2];
    const float* b_ih = (const float*)d_in[3];
    const float* b_hh = (const float*)d_in[4];
    const float* w_v  = (const float*)d_in[5];
    const float* w_w  = (const float*)d_in[6];
    const float* b_w  = (const float*)d_in[7];
    const float* w_u  = (const float*)d_in[8];
    const float* b_u  = (const float*)d_in[9];

    float* out_xt = (float*)d_out;
    float* out_h  = out_xt + 64*512*256;

    const size_t shbytes = (size_t)L_TOT * sizeof(float);  // 149568 B
    (void)hipFuncSetAttribute((const void*)enc_kernel,
                        hipFuncAttributeMaxDynamicSharedMemorySize, (int)shbytes);
    enc_kernel<<<dim3(256), dim3(512), shbytes, stream>>>(
        x, w_ih, w_hh, b_ih, b_hh, w_v, w_w, b_w, w_u, b_u, out_xt, out_h);
}